// Round 1
// baseline (147.238 us; speedup 1.0000x reference)
//
#include <hip/hip_runtime.h>
#include <hip/hip_bf16.h>
#include <math.h>

#define NPATH 6
#define NINST 20000
#define PLEN 4
#define DFEAT 128
#define TOTAL (NPATH * NINST)

// ---------------------------------------------------------------------------
// Kernel 0: precompute u1[m] = W_enc[m] @ W_att[e, :128],
//                      u2[m] = W_enc[m] @ W_att[e, 128:256],
//                      c[m]  = b_enc[m]·(Wa1+Wa2) + b_att[e]
// grid = 6 blocks, 128 threads
// ---------------------------------------------------------------------------
__global__ void k_pre(const float* __restrict__ W_enc, const float* __restrict__ b_enc,
                      const float* __restrict__ W_att, const float* __restrict__ b_att,
                      const int* __restrict__ etype,
                      float* __restrict__ u1, float* __restrict__ u2, float* __restrict__ cvec) {
    int m = blockIdx.x;
    int d = threadIdx.x;          // 0..127
    int e = etype[m];
    const float* W  = W_enc + (size_t)m * DFEAT * DFEAT + (size_t)d * DFEAT; // row d of W_enc[m]
    const float* wa = W_att + (size_t)e * (2 * DFEAT);
    float s1 = 0.f, s2 = 0.f;
    for (int h = 0; h < DFEAT; ++h) {
        float w = W[h];
        s1 += w * wa[h];
        s2 += w * wa[DFEAT + h];
    }
    u1[m * DFEAT + d] = s1;
    u2[m * DFEAT + d] = s2;

    __shared__ float sd[DFEAT];
    sd[d] = b_enc[m * DFEAT + d] * (wa[d] + wa[DFEAT + d]);
    __syncthreads();
    for (int off = 64; off; off >>= 1) {
        if (d < off) sd[d] += sd[d + off];
        __syncthreads();
    }
    if (d == 0) cvec[m] = sd[0] + b_att[e];
}

// ---------------------------------------------------------------------------
// Kernel 1: scores[m,i] = leaky_relu( g0·u1[m] + g3·u2[m] + c[m], 0.2 )
// one instance per wave; lanes 0-31 read row(first) as float4, lanes 32-63 row(last)
// ---------------------------------------------------------------------------
__global__ void k_scores(const float* __restrict__ feat, const int* __restrict__ inst,
                         const float* __restrict__ u1, const float* __restrict__ u2,
                         const float* __restrict__ cvec, float* __restrict__ scores,
                         int waves_total) {
    int lane = threadIdx.x & 63;
    int wave = blockIdx.x * (blockDim.x >> 6) + (threadIdx.x >> 6);
    int half = lane >> 5;     // 0: first pos, 1: last pos
    int sub  = lane & 31;

    for (int t = wave; t < TOTAL; t += waves_total) {
        int m = t / NINST;
        int node = inst[(size_t)t * PLEN + (half ? (PLEN - 1) : 0)];
        const float4* row = (const float4*)(feat + (size_t)node * DFEAT);
        const float4* uv  = (const float4*)((half ? u2 : u1) + m * DFEAT);
        float4 f = row[sub];
        float4 u = uv[sub];
        float p = f.x * u.x + f.y * u.y + f.z * u.z + f.w * u.w;
        // 64-lane sum: combines both halves => dot0 + dot1
        for (int o = 32; o; o >>= 1) p += __shfl_xor(p, o);
        if (lane == 0) {
            float s = p + cvec[m];
            s = s > 0.f ? s : 0.2f * s;   // leaky_relu(0.2)
            scores[t] = s;
        }
    }
}

// ---------------------------------------------------------------------------
// Kernel 2: per-path softmax over 20000 scores, normalized weights in place
// grid = 6 blocks, 256 threads
// ---------------------------------------------------------------------------
__global__ void k_softmax(float* __restrict__ scores) {
    int m = blockIdx.x;
    float* s = scores + (size_t)m * NINST;
    int tid = threadIdx.x, lane = tid & 63, w = tid >> 6;
    __shared__ float red[4];

    float mx = -1e30f;
    for (int i = tid; i < NINST; i += blockDim.x) mx = fmaxf(mx, s[i]);
    for (int o = 32; o; o >>= 1) mx = fmaxf(mx, __shfl_xor(mx, o));
    if (lane == 0) red[w] = mx;
    __syncthreads();
    mx = fmaxf(fmaxf(red[0], red[1]), fmaxf(red[2], red[3]));
    __syncthreads();

    float sm = 0.f;
    for (int i = tid; i < NINST; i += blockDim.x) sm += expf(s[i] - mx);
    for (int o = 32; o; o >>= 1) sm += __shfl_xor(sm, o);
    if (lane == 0) red[w] = sm;
    __syncthreads();
    float inv = 1.f / (red[0] + red[1] + red[2] + red[3]);

    for (int i = tid; i < NINST; i += blockDim.x) s[i] = expf(s[i] - mx) * inv;
}

// ---------------------------------------------------------------------------
// Kernel 3: v[m][d] = sum_i w[m,i] * feat[last(m,i)][d]
// one instance per wave per iter; lane l owns d = 2l, 2l+1 (float2)
// LDS reduce across the block's 4 waves, then atomicAdd into v (768 floats)
// ---------------------------------------------------------------------------
#define BPER 128   // blocks per path
__global__ void k_accum(const float* __restrict__ feat, const int* __restrict__ inst,
                        const float* __restrict__ w, float* __restrict__ v) {
    int m  = blockIdx.x / BPER;
    int b  = blockIdx.x % BPER;
    int lane = threadIdx.x & 63, wv = threadIdx.x >> 6;
    const int wavesPerPath = BPER * 4;

    float a0 = 0.f, a1 = 0.f;
    for (int i = b * 4 + wv; i < NINST; i += wavesPerPath) {
        int t = m * NINST + i;
        int node = inst[(size_t)t * PLEN + (PLEN - 1)];
        float wt = w[t];
        const float2* row = (const float2*)(feat + (size_t)node * DFEAT);
        float2 f = row[lane];
        a0 += wt * f.x;
        a1 += wt * f.y;
    }
    __shared__ float sd[4][DFEAT];
    sd[wv][2 * lane]     = a0;
    sd[wv][2 * lane + 1] = a1;
    __syncthreads();
    int tid = threadIdx.x;
    if (tid < DFEAT) {
        float t = sd[0][tid] + sd[1][tid] + sd[2][tid] + sd[3][tid];
        atomicAdd(&v[m * DFEAT + tid], t);
    }
}

// ---------------------------------------------------------------------------
// Kernel 4: mp_out[m] = v[m] @ W_enc[m] + b_enc[m]; path softmax; out = elu(...)
// 1 block, 128 threads (thread = output dim h)
// ---------------------------------------------------------------------------
__global__ void k_final(const float* __restrict__ v, const float* __restrict__ W_enc,
                        const float* __restrict__ b_enc, const float* __restrict__ w_mp,
                        const float* __restrict__ b_mp, float* __restrict__ out) {
    int h = threadIdx.x;  // 0..127
    float mp[NPATH];
    for (int m = 0; m < NPATH; ++m) {
        float acc = b_enc[m * DFEAT + h];
        const float* vm = v + m * DFEAT;
        const float* W  = W_enc + (size_t)m * DFEAT * DFEAT;
        for (int d = 0; d < DFEAT; ++d) acc += vm[d] * W[(size_t)d * DFEAT + h];
        mp[m] = acc;
    }

    __shared__ float sd[DFEAT];
    __shared__ float ms[NPATH];
    for (int m = 0; m < NPATH; ++m) {
        sd[h] = mp[m] * w_mp[h];
        __syncthreads();
        for (int off = 64; off; off >>= 1) {
            if (h < off) sd[h] += sd[h + off];
            __syncthreads();
        }
        if (h == 0) ms[m] = sd[0] + b_mp[0];
        __syncthreads();
    }

    // softmax(leaky_relu(ms)) over the 6 paths (every thread redundantly)
    float l[NPATH], mx = -1e30f;
    for (int m = 0; m < NPATH; ++m) {
        float x = ms[m];
        x = x > 0.f ? x : 0.2f * x;
        l[m] = x;
        mx = fmaxf(mx, x);
    }
    float sum = 0.f;
    for (int m = 0; m < NPATH; ++m) { l[m] = expf(l[m] - mx); sum += l[m]; }
    float o = 0.f;
    for (int m = 0; m < NPATH; ++m) o += (l[m] / sum) * mp[m];
    out[h] = o > 0.f ? o : expf(o) - 1.f;   // elu
}

// ---------------------------------------------------------------------------
extern "C" void kernel_launch(void* const* d_in, const int* in_sizes, int n_in,
                              void* d_out, int out_size, void* d_ws, size_t ws_size,
                              hipStream_t stream) {
    const float* features  = (const float*)d_in[0];
    const float* W_enc     = (const float*)d_in[1];
    const float* b_enc     = (const float*)d_in[2];
    const float* W_att     = (const float*)d_in[3];
    const float* b_att     = (const float*)d_in[4];
    const float* w_mp      = (const float*)d_in[5];
    const float* b_mp      = (const float*)d_in[6];
    const int*   instances = (const int*)d_in[7];
    const int*   edge_types= (const int*)d_in[8];
    float* out = (float*)d_out;
    float* ws  = (float*)d_ws;

    // workspace layout (floats)
    float* u1     = ws;                 // 768
    float* u2     = ws + 768;           // 768
    float* cvec   = ws + 1536;          // 6 (padded to 1600)
    float* scores = ws + 1600;          // 120000
    float* v      = ws + 1600 + TOTAL;  // 768

    hipMemsetAsync(v, 0, NPATH * DFEAT * sizeof(float), stream);

    k_pre<<<NPATH, DFEAT, 0, stream>>>(W_enc, b_enc, W_att, b_att, edge_types, u1, u2, cvec);

    const int blocks1 = 1024;
    k_scores<<<blocks1, 256, 0, stream>>>(features, instances, u1, u2, cvec, scores, blocks1 * 4);

    k_softmax<<<NPATH, 256, 0, stream>>>(scores);

    k_accum<<<NPATH * BPER, 256, 0, stream>>>(features, instances, scores, v);

    k_final<<<1, DFEAT, 0, stream>>>(v, W_enc, b_enc, w_mp, b_mp, out);
}

// Round 2
// 95.230 us; speedup vs baseline: 1.5461x; 1.5461x over previous
//
#include <hip/hip_runtime.h>
#include <hip/hip_bf16.h>
#include <math.h>

#define NPATH 6
#define NINST 20000
#define PLEN 4
#define DFEAT 128
#define WPP 512              // waves per path in pass1
#define BPP (WPP / 4)        // blocks per path (4 waves/block)

// ---------------------------------------------------------------------------
// Kernel 0: u1[m] = W_enc[m] @ Wa1,  u2[m] = W_enc[m] @ Wa2,
//           c[m]  = b_enc[m]·(Wa1+Wa2) + b_att[e]
// grid = 6 blocks × 128 threads
// ---------------------------------------------------------------------------
__global__ void k_pre(const float* __restrict__ W_enc, const float* __restrict__ b_enc,
                      const float* __restrict__ W_att, const float* __restrict__ b_att,
                      const int* __restrict__ etype,
                      float* __restrict__ u1, float* __restrict__ u2, float* __restrict__ cvec) {
    int m = blockIdx.x;
    int d = threadIdx.x;          // 0..127
    int e = etype[m];
    const float* wa = W_att + (size_t)e * (2 * DFEAT);

    __shared__ float swa[2 * DFEAT];
    swa[d] = wa[d];
    swa[d + DFEAT] = wa[d + DFEAT];
    __syncthreads();

    const float4* W = (const float4*)(W_enc + (size_t)m * DFEAT * DFEAT + (size_t)d * DFEAT);
    float s1 = 0.f, s2 = 0.f;
    #pragma unroll 8
    for (int q = 0; q < DFEAT / 4; ++q) {
        float4 wv = W[q];
        s1 += wv.x * swa[4*q]         + wv.y * swa[4*q+1]
            + wv.z * swa[4*q+2]       + wv.w * swa[4*q+3];
        s2 += wv.x * swa[DFEAT+4*q]   + wv.y * swa[DFEAT+4*q+1]
            + wv.z * swa[DFEAT+4*q+2] + wv.w * swa[DFEAT+4*q+3];
    }
    u1[m * DFEAT + d] = s1;
    u2[m * DFEAT + d] = s2;

    __shared__ float sd[DFEAT];
    sd[d] = b_enc[m * DFEAT + d] * (swa[d] + swa[DFEAT + d]);
    __syncthreads();
    for (int off = 64; off; off >>= 1) {
        if (d < off) sd[d] += sd[d + off];
        __syncthreads();
    }
    if (d == 0) cvec[m] = sd[0] + b_att[e];
}

// ---------------------------------------------------------------------------
// Kernel 1: fused score + online-softmax weighted accumulation.
// One instance per wave per iter; lane l owns dims {2l, 2l+1}.
// score s = g0·u1 + g3·u2 + c  (64-lane butterfly reduce-all)
// online:  ns=max(m,s); scale=e^(m-ns); p=e^(s-ns);
//          sum=sum*scale+p; V=V*scale+p*g3lane; m=ns
// Per wave out: V[128], m, sum.
// grid = NPATH*BPP blocks × 256 threads
// ---------------------------------------------------------------------------
__global__ void k_pass1(const float* __restrict__ feat, const int* __restrict__ inst,
                        const float* __restrict__ u1, const float* __restrict__ u2,
                        const float* __restrict__ cvec,
                        float* __restrict__ pV, float* __restrict__ pM, float* __restrict__ pS) {
    int m    = blockIdx.x / BPP;
    int bw   = blockIdx.x % BPP;
    int wv   = threadIdx.x >> 6;
    int lane = threadIdx.x & 63;
    int w    = bw * 4 + wv;                    // wave within path [0, WPP)

    float2 U1 = ((const float2*)(u1 + m * DFEAT))[lane];
    float2 U2 = ((const float2*)(u2 + m * DFEAT))[lane];
    float c   = cvec[m];

    const int* ibase = inst + (size_t)m * NINST * PLEN;

    float mx = -3e38f, sum = 0.f, v0 = 0.f, v1 = 0.f;

    int i = w;
    float2 f0, f3;
    {   // prologue load
        int n0 = ibase[i * PLEN];
        int n3 = ibase[i * PLEN + 3];
        f0 = ((const float2*)(feat + (size_t)n0 * DFEAT))[lane];
        f3 = ((const float2*)(feat + (size_t)n3 * DFEAT))[lane];
    }
    while (i < NINST) {
        int inext = i + WPP;
        float2 g0, g3;
        if (inext < NINST) {    // software-pipelined prefetch of next rows
            int n0 = ibase[inext * PLEN];
            int n3 = ibase[inext * PLEN + 3];
            g0 = ((const float2*)(feat + (size_t)n0 * DFEAT))[lane];
            g3 = ((const float2*)(feat + (size_t)n3 * DFEAT))[lane];
        }
        float p = f0.x * U1.x + f0.y * U1.y + f3.x * U2.x + f3.y * U2.y;
        #pragma unroll
        for (int o = 32; o; o >>= 1) p += __shfl_xor(p, o);
        float s = p + c;
        s = s > 0.f ? s : 0.2f * s;            // leaky_relu(0.2)
        float ns    = fmaxf(mx, s);
        float scale = __expf(mx - ns);
        float pe    = __expf(s - ns);
        sum = sum * scale + pe;
        v0  = v0  * scale + pe * f3.x;
        v1  = v1  * scale + pe * f3.y;
        mx  = ns;

        f0 = g0; f3 = g3;
        i = inext;
    }

    int p = m * WPP + w;
    pV[(size_t)p * DFEAT + 2 * lane]     = v0;
    pV[(size_t)p * DFEAT + 2 * lane + 1] = v1;
    if (lane == 0) { pM[p] = mx; pS[p] = sum; }
}

// ---------------------------------------------------------------------------
// Kernel 2: per path — combine WPP partials, normalize, GEMV with W_enc,
// compute mp_out[m][:] and ms[m].
// grid = 6 blocks × 512 threads
// ---------------------------------------------------------------------------
__global__ void k_pass2(const float* __restrict__ pV, const float* __restrict__ pM,
                        const float* __restrict__ pS,
                        const float* __restrict__ W_enc, const float* __restrict__ b_enc,
                        const float* __restrict__ w_mp, const float* __restrict__ b_mp,
                        float* __restrict__ mp_out, float* __restrict__ ms) {
    int m   = blockIdx.x;
    int tid = threadIdx.x;
    int lane = tid & 63, wvi = tid >> 6;

    __shared__ float e[WPP];
    __shared__ float red[8];
    __shared__ float sS, sMx;
    __shared__ float sv[4][DFEAT];
    __shared__ float sVn[DFEAT];

    // 1) global max over WPP wave maxima (WPP == blockDim.x)
    float mx = pM[m * WPP + tid];
    #pragma unroll
    for (int o = 32; o; o >>= 1) mx = fmaxf(mx, __shfl_xor(mx, o));
    if (lane == 0) red[wvi] = mx;
    __syncthreads();
    if (tid == 0) {
        float t = red[0];
        for (int k = 1; k < 8; ++k) t = fmaxf(t, red[k]);
        sMx = t;
    }
    __syncthreads();
    float M = sMx;

    // 2) e_w = exp(m_w - M);  S = sum_w e_w * sum_w
    float ew = __expf(pM[m * WPP + tid] - M);
    e[tid] = ew;
    float ssum = ew * pS[m * WPP + tid];
    #pragma unroll
    for (int o = 32; o; o >>= 1) ssum += __shfl_xor(ssum, o);
    if (lane == 0) red[wvi] = ssum;
    __syncthreads();
    if (tid == 0) {
        float t = 0.f;
        for (int k = 0; k < 8; ++k) t += red[k];
        sS = t;
    }
    __syncthreads();
    float Sinv = 1.f / sS;

    // 3) V[d] = sum_w e_w * pV[w][d]
    int d = tid & 127, slice = tid >> 7;      // slice in [0,4)
    float acc = 0.f;
    for (int wIdx = slice; wIdx < WPP; wIdx += 4)
        acc += e[wIdx] * pV[((size_t)(m * WPP + wIdx)) * DFEAT + d];
    sv[slice][d] = acc;
    __syncthreads();
    if (tid < DFEAT) sVn[tid] = (sv[0][tid] + sv[1][tid] + sv[2][tid] + sv[3][tid]) * Sinv;
    __syncthreads();

    // 4) GEMV: mp[h] = sVn · W[:,h] + b_enc[m][h]
    const float* W = W_enc + (size_t)m * DFEAT * DFEAT;
    int h = tid & 127;
    float g = 0.f;
    for (int dd = slice; dd < DFEAT; dd += 4)
        g += sVn[dd] * W[(size_t)dd * DFEAT + h];
    __syncthreads();   // sv reuse
    sv[slice][h] = g;
    __syncthreads();
    __shared__ float smp[DFEAT];
    if (tid < DFEAT) {
        float t = sv[0][tid] + sv[1][tid] + sv[2][tid] + sv[3][tid] + b_enc[m * DFEAT + tid];
        mp_out[m * DFEAT + tid] = t;
        smp[tid] = t * w_mp[tid];
    }
    __syncthreads();

    // 5) ms[m] = mp · w_mp + b_mp
    if (tid < 64) {
        float t = smp[tid] + smp[tid + 64];
        #pragma unroll
        for (int o = 32; o; o >>= 1) t += __shfl_xor(t, o);
        if (tid == 0) ms[m] = t + b_mp[0];
    }
}

// ---------------------------------------------------------------------------
// Kernel 3: cross-path softmax(leaky_relu(ms)) + blend + ELU.  1 block × 128.
// ---------------------------------------------------------------------------
__global__ void k_final(const float* __restrict__ mp_out, const float* __restrict__ ms,
                        float* __restrict__ out) {
    int h = threadIdx.x;
    float l[NPATH], mx = -3e38f;
    #pragma unroll
    for (int m = 0; m < NPATH; ++m) {
        float x = ms[m];
        x = x > 0.f ? x : 0.2f * x;
        l[m] = x;
        mx = fmaxf(mx, x);
    }
    float sum = 0.f;
    #pragma unroll
    for (int m = 0; m < NPATH; ++m) { l[m] = __expf(l[m] - mx); sum += l[m]; }
    float o = 0.f;
    #pragma unroll
    for (int m = 0; m < NPATH; ++m) o += (l[m] / sum) * mp_out[m * DFEAT + h];
    out[h] = o > 0.f ? o : __expf(o) - 1.f;   // elu
}

// ---------------------------------------------------------------------------
extern "C" void kernel_launch(void* const* d_in, const int* in_sizes, int n_in,
                              void* d_out, int out_size, void* d_ws, size_t ws_size,
                              hipStream_t stream) {
    const float* features   = (const float*)d_in[0];
    const float* W_enc      = (const float*)d_in[1];
    const float* b_enc      = (const float*)d_in[2];
    const float* W_att      = (const float*)d_in[3];
    const float* b_att      = (const float*)d_in[4];
    const float* w_mp       = (const float*)d_in[5];
    const float* b_mp       = (const float*)d_in[6];
    const int*   instances  = (const int*)d_in[7];
    const int*   edge_types = (const int*)d_in[8];
    float* out = (float*)d_out;
    float* ws  = (float*)d_ws;

    // workspace layout (floats)
    float* u1     = ws;                        // 768
    float* u2     = ws + 768;                  // 768
    float* cvec   = ws + 1536;                 // 6  (pad to 1600)
    float* pV     = ws + 1600;                 // WPP*NPATH*128 = 393216
    float* pM     = pV + (size_t)WPP * NPATH * DFEAT;   // 3072
    float* pS     = pM + WPP * NPATH;                   // 3072
    float* mp_out = pS + WPP * NPATH;                   // 768
    float* msv    = mp_out + NPATH * DFEAT;             // 6

    k_pre<<<NPATH, DFEAT, 0, stream>>>(W_enc, b_enc, W_att, b_att, edge_types, u1, u2, cvec);

    k_pass1<<<NPATH * BPP, 256, 0, stream>>>(features, instances, u1, u2, cvec, pV, pM, pS);

    k_pass2<<<NPATH, WPP, 0, stream>>>(pV, pM, pS, W_enc, b_enc, w_mp, b_mp, mp_out, msv);

    k_final<<<1, DFEAT, 0, stream>>>(mp_out, msv, out);
}